// Round 1
// baseline (1165.410 us; speedup 1.0000x reference)
//
#include <hip/hip_runtime.h>
#include <hip/hip_bf16.h>
#include <stdint.h>

typedef __attribute__((ext_vector_type(4))) float f32x4;
typedef __attribute__((ext_vector_type(8))) __bf16 bf16x8;
typedef __attribute__((ext_vector_type(4))) unsigned short u16x4;
typedef unsigned short u16;

#define NTOK 8192
#define DDIM 1024
#define FDIM 4096
#define NEXP 8

// ---- workspace layout (bytes) ----
#define WS_XB    0ull                          // 8192*1024*2        = 16,777,216
#define WS_W1T   (16777216ull)                 // 8*8192*1024*2      = 134,217,728
#define WS_W2T   (WS_W1T + 134217728ull)       // 8*1024*4096*2      = 67,108,864
#define WS_ACT   (WS_W2T + 67108864ull)        // 17408*4096*2       = 142,606,336
#define WS_LIST  (WS_ACT + 142606336ull)       // 8*8192*4           = 262,144
#define WS_PAIRW (WS_LIST + 262144ull)         // 8*8192*4           = 262,144
#define WS_CNT   (WS_PAIRW + 262144ull)        // 8 int
#define WS_SUMP  (WS_CNT + 32ull)              // 8 float
#define WS_PAD   (WS_SUMP + 32ull)             // 8 int
#define WS_OFF   (WS_PAD + 32ull)              // 8 int

static __device__ __forceinline__ u16 bf16rne(float f) {
  union { float f; uint32_t u; } c; c.f = f;
  return (u16)((c.u + 0x7FFFu + ((c.u >> 16) & 1u)) >> 16);
}

static __device__ __forceinline__ void load_lds16(const void* g, void* l) {
  __builtin_amdgcn_global_load_lds((const __attribute__((address_space(1))) void*)g,
                                   (__attribute__((address_space(3))) void*)l, 16, 0, 0);
}

// ---------------- gating + routing + x->bf16 ----------------
__global__ __launch_bounds__(256) void gate_kernel(
    const float* __restrict__ x, const float* __restrict__ gw,
    const float* __restrict__ gb, u16* __restrict__ xb,
    int* __restrict__ cnt, float* __restrict__ sump,
    int* __restrict__ list, float* __restrict__ pairw) {
  const int tid = threadIdx.x;
  const int lane = tid & 63;
  const int wv = tid >> 6;
  const int t = blockIdx.x * 4 + wv;

  __shared__ float sp[8];
  if (tid < 8) sp[tid] = 0.f;
  __syncthreads();

  float acc[8] = {0.f,0.f,0.f,0.f,0.f,0.f,0.f,0.f};
  const float4* x4 = (const float4*)x + (size_t)t * 256;
  u16x4* xb4 = (u16x4*)xb + (size_t)t * 256;
  #pragma unroll
  for (int it = 0; it < 4; ++it) {
    const float4 xv = x4[it * 64 + lane];
    u16x4 bv;
    bv[0] = bf16rne(xv.x); bv[1] = bf16rne(xv.y);
    bv[2] = bf16rne(xv.z); bv[3] = bf16rne(xv.w);
    xb4[it * 64 + lane] = bv;
    const int d0 = (it * 64 + lane) * 4;
    #pragma unroll
    for (int j = 0; j < 4; ++j) {
      const float xs = (j == 0) ? xv.x : ((j == 1) ? xv.y : ((j == 2) ? xv.z : xv.w));
      const float* g = gw + (size_t)(d0 + j) * 8;
      #pragma unroll
      for (int e2 = 0; e2 < 8; ++e2) acc[e2] += xs * g[e2];
    }
  }
  #pragma unroll
  for (int e2 = 0; e2 < 8; ++e2) {
    float v = acc[e2];
    v += __shfl_xor(v, 1);  v += __shfl_xor(v, 2);  v += __shfl_xor(v, 4);
    v += __shfl_xor(v, 8);  v += __shfl_xor(v, 16); v += __shfl_xor(v, 32);
    acc[e2] = v;
  }
  float p[8]; float mx = -1e30f;
  #pragma unroll
  for (int e2 = 0; e2 < 8; ++e2) { p[e2] = acc[e2] + gb[e2]; mx = fmaxf(mx, p[e2]); }
  float s = 0.f;
  #pragma unroll
  for (int e2 = 0; e2 < 8; ++e2) { p[e2] = expf(p[e2] - mx); s += p[e2]; }
  const float inv = 1.f / s;
  #pragma unroll
  for (int e2 = 0; e2 < 8; ++e2) p[e2] *= inv;

  if (lane == 0) {
    int i1 = 0; float v1 = p[0];
    #pragma unroll
    for (int e2 = 1; e2 < 8; ++e2) if (p[e2] > v1) { v1 = p[e2]; i1 = e2; }
    int i2 = 0; float v2 = -1.f;
    #pragma unroll
    for (int e2 = 0; e2 < 8; ++e2) if (e2 != i1 && p[e2] > v2) { v2 = p[e2]; i2 = e2; }
    const float den = v1 + v2 + 1e-6f;
    const int p1 = atomicAdd(&cnt[i1], 1);
    list[i1 * NTOK + p1] = t; pairw[i1 * NTOK + p1] = v1 / den;
    const int p2 = atomicAdd(&cnt[i2], 1);
    list[i2 * NTOK + p2] = t; pairw[i2 * NTOK + p2] = v2 / den;
    #pragma unroll
    for (int e2 = 0; e2 < 8; ++e2) atomicAdd(&sp[e2], p[e2]);
  }
  __syncthreads();
  if (tid < 8) atomicAdd(&sump[tid], sp[tid]);
}

// ---------------- fp32 [R][C] -> bf16 [C][R] transpose ----------------
__global__ __launch_bounds__(256) void conv_transpose(
    const float* __restrict__ in, u16* __restrict__ out, int R, int C) {
  __shared__ float tile[64][65];
  const int e = blockIdx.z;
  const float* pin = in + (size_t)e * R * C;
  u16* pout = out + (size_t)e * R * C;
  const int tx = threadIdx.x & 15;
  const int ty = threadIdx.x >> 4;
  const int c0 = blockIdx.x * 64;
  const int r0 = blockIdx.y * 64;
  #pragma unroll
  for (int i = 0; i < 4; ++i) {
    const int r = ty + i * 16;
    const float4 v = *(const float4*)(pin + (size_t)(r0 + r) * C + c0 + tx * 4);
    tile[r][tx * 4 + 0] = v.x;
    tile[r][tx * 4 + 1] = v.y;
    tile[r][tx * 4 + 2] = v.z;
    tile[r][tx * 4 + 3] = v.w;
  }
  __syncthreads();
  #pragma unroll
  for (int i = 0; i < 4; ++i) {
    const int c = ty + i * 16;
    u16x4 o;
    o[0] = bf16rne(tile[tx * 4 + 0][c]);
    o[1] = bf16rne(tile[tx * 4 + 1][c]);
    o[2] = bf16rne(tile[tx * 4 + 2][c]);
    o[3] = bf16rne(tile[tx * 4 + 3][c]);
    *(u16x4*)(pout + (size_t)(c0 + c) * R + r0 + tx * 4) = o;
  }
}

// ---------------- routing finalize: offsets, padding, lb loss ----------------
__global__ void route_finalize(const int* __restrict__ cnt, const float* __restrict__ sump,
                               int* __restrict__ padc, int* __restrict__ offs,
                               int* __restrict__ list, float* __restrict__ pairw,
                               float* __restrict__ lb_out) {
  __shared__ int s_c[8], s_p[8];
  const int tid = threadIdx.x;
  if (tid == 0) {
    int o = 0; float lb = 0.f;
    for (int e = 0; e < 8; ++e) {
      const int c = cnt[e];
      const int pc = (c + 127) & ~127;
      s_c[e] = c; s_p[e] = pc;
      padc[e] = pc; offs[e] = o; o += pc;
      lb += ((float)c / 8192.f) * (sump[e] / 8192.f);
    }
    lb_out[0] = 0.01f * 8.f * lb;
  }
  __syncthreads();
  for (int e = 0; e < 8; ++e)
    for (int pq = s_c[e] + tid; pq < s_p[e]; pq += blockDim.x) {
      list[e * NTOK + pq] = 0; pairw[e * NTOK + pq] = 0.f;
    }
}

// ---------------- GEMM1: xb[rows] @ w1t^T, fused SwiGLU -> act ----------------
// B-tile rows interleave a/g column groups so SwiGLU pairs are register-local.
__global__ __launch_bounds__(256) void gemm1_kernel(
    const u16* __restrict__ xb, const u16* __restrict__ w1t,
    const float* __restrict__ b1, const int* __restrict__ list,
    const int* __restrict__ padc, const int* __restrict__ offs,
    u16* __restrict__ act) {
  const int e = blockIdx.z;
  const int ti = blockIdx.y;
  if (ti * 128 >= padc[e]) return;
  const int j = blockIdx.x;
  const int off_e = offs[e];

  __shared__ u16 lsA[2][128 * 32];
  __shared__ u16 lsB[2][128 * 32];

  const int tid = threadIdx.x;
  const int lane = tid & 63;
  const int wv = tid >> 6;
  const int wr = wv >> 1, wc = wv & 1;
  const int kq = lane & 3;

  const u16* srcA[2]; const u16* srcB[2];
  u16* dstA[2]; u16* dstB[2];
  #pragma unroll
  for (int i = 0; i < 2; ++i) {
    const int sl = (i * 4 + wv) * 64 + lane;
    const int r = sl >> 2;
    const int tok = list[e * NTOK + ti * 128 + r];
    srcA[i] = xb + (size_t)tok * DDIM + kq * 8;
    const int g16 = r >> 4;
    const int gn = j * 64 + (g16 >> 1) * 16 + (r & 15) + ((g16 & 1) ? FDIM : 0);
    srcB[i] = w1t + ((size_t)e * 2 * FDIM + gn) * DDIM + kq * 8;
    dstA[i] = &lsA[0][(i * 4 + wv) * 512];
    dstB[i] = &lsB[0][(i * 4 + wv) * 512];
  }

  f32x4 acc[4][4];
  #pragma unroll
  for (int m = 0; m < 4; ++m)
    #pragma unroll
    for (int n = 0; n < 4; ++n) {
      acc[m][n][0] = 0.f; acc[m][n][1] = 0.f; acc[m][n][2] = 0.f; acc[m][n][3] = 0.f;
    }

  #pragma unroll
  for (int i = 0; i < 2; ++i) { load_lds16(srcA[i], dstA[i]); load_lds16(srcB[i], dstB[i]); }

  const int aRow = wr * 64 + (lane & 15);
  const int bRow = wc * 64 + (lane & 15);
  const int kOff = (lane >> 4) * 8;

  for (int kt = 0; kt < DDIM / 32; ++kt) {
    const int cur = kt & 1;
    __syncthreads();
    if (kt + 1 < DDIM / 32) {
      const int k0 = (kt + 1) * 32;
      const int bufo = (cur ^ 1) * (128 * 32);
      #pragma unroll
      for (int i = 0; i < 2; ++i) {
        load_lds16(srcA[i] + k0, dstA[i] + bufo);
        load_lds16(srcB[i] + k0, dstB[i] + bufo);
      }
    }
    const int base = cur * (128 * 32);
    bf16x8 aF[4], bF[4];
    #pragma unroll
    for (int m = 0; m < 4; ++m) aF[m] = *(const bf16x8*)(&lsA[0][base + (aRow + m * 16) * 32 + kOff]);
    #pragma unroll
    for (int n = 0; n < 4; ++n) bF[n] = *(const bf16x8*)(&lsB[0][base + (bRow + n * 16) * 32 + kOff]);
    #pragma unroll
    for (int m = 0; m < 4; ++m)
      #pragma unroll
      for (int n = 0; n < 4; ++n)
        acc[m][n] = __builtin_amdgcn_mfma_f32_16x16x32_bf16(aF[m], bF[n], acc[m][n], 0, 0, 0);
  }

  const int l15 = lane & 15;
  const int l4 = lane >> 4;
  #pragma unroll
  for (int pp = 0; pp < 2; ++pp) {
    const int col = j * 64 + wc * 32 + pp * 16 + l15;
    const float ba = b1[e * (2 * FDIM) + col];
    const float bg = b1[e * (2 * FDIM) + FDIM + col];
    #pragma unroll
    for (int m = 0; m < 4; ++m) {
      #pragma unroll
      for (int jr = 0; jr < 4; ++jr) {
        const int rl = wr * 64 + m * 16 + l4 * 4 + jr;
        const float a = acc[m][2 * pp][jr] + ba;
        const float g = acc[m][2 * pp + 1][jr] + bg;
        const float gg = 0.5f * g * (1.f + erff(g * 0.70710678118654752f));
        act[(size_t)(off_e + ti * 128 + rl) * FDIM + col] = bf16rne(a * gg);
      }
    }
  }
}

// ---------------- GEMM2: act @ w2t^T, scale by combine weight, atomic out ----------------
__global__ __launch_bounds__(256) void gemm2_kernel(
    const u16* __restrict__ act, const u16* __restrict__ w2t,
    const float* __restrict__ b2, const int* __restrict__ list,
    const float* __restrict__ pairw, const int* __restrict__ padc,
    const int* __restrict__ offs, float* __restrict__ out) {
  const int e = blockIdx.z;
  const int ti = blockIdx.y;
  if (ti * 128 >= padc[e]) return;
  const int jt = blockIdx.x;
  const int off_e = offs[e];

  __shared__ u16 lsA[2][128 * 32];
  __shared__ u16 lsB[2][128 * 32];

  const int tid = threadIdx.x;
  const int lane = tid & 63;
  const int wv = tid >> 6;
  const int wr = wv >> 1, wc = wv & 1;
  const int kq = lane & 3;

  const u16* srcA[2]; const u16* srcB[2];
  u16* dstA[2]; u16* dstB[2];
  #pragma unroll
  for (int i = 0; i < 2; ++i) {
    const int sl = (i * 4 + wv) * 64 + lane;
    const int r = sl >> 2;
    srcA[i] = act + (size_t)(off_e + ti * 128 + r) * FDIM + kq * 8;
    srcB[i] = w2t + ((size_t)e * DDIM + jt * 128 + r) * FDIM + kq * 8;
    dstA[i] = &lsA[0][(i * 4 + wv) * 512];
    dstB[i] = &lsB[0][(i * 4 + wv) * 512];
  }

  f32x4 acc[4][4];
  #pragma unroll
  for (int m = 0; m < 4; ++m)
    #pragma unroll
    for (int n = 0; n < 4; ++n) {
      acc[m][n][0] = 0.f; acc[m][n][1] = 0.f; acc[m][n][2] = 0.f; acc[m][n][3] = 0.f;
    }

  #pragma unroll
  for (int i = 0; i < 2; ++i) { load_lds16(srcA[i], dstA[i]); load_lds16(srcB[i], dstB[i]); }

  const int aRow = wr * 64 + (lane & 15);
  const int bRow = wc * 64 + (lane & 15);
  const int kOff = (lane >> 4) * 8;

  for (int kt = 0; kt < FDIM / 32; ++kt) {
    const int cur = kt & 1;
    __syncthreads();
    if (kt + 1 < FDIM / 32) {
      const int k0 = (kt + 1) * 32;
      const int bufo = (cur ^ 1) * (128 * 32);
      #pragma unroll
      for (int i = 0; i < 2; ++i) {
        load_lds16(srcA[i] + k0, dstA[i] + bufo);
        load_lds16(srcB[i] + k0, dstB[i] + bufo);
      }
    }
    const int base = cur * (128 * 32);
    bf16x8 aF[4], bF[4];
    #pragma unroll
    for (int m = 0; m < 4; ++m) aF[m] = *(const bf16x8*)(&lsA[0][base + (aRow + m * 16) * 32 + kOff]);
    #pragma unroll
    for (int n = 0; n < 4; ++n) bF[n] = *(const bf16x8*)(&lsB[0][base + (bRow + n * 16) * 32 + kOff]);
    #pragma unroll
    for (int m = 0; m < 4; ++m)
      #pragma unroll
      for (int n = 0; n < 4; ++n)
        acc[m][n] = __builtin_amdgcn_mfma_f32_16x16x32_bf16(aF[m], bF[n], acc[m][n], 0, 0, 0);
  }

  const int l15 = lane & 15;
  const int l4 = lane >> 4;
  #pragma unroll
  for (int m = 0; m < 4; ++m) {
    #pragma unroll
    for (int jr = 0; jr < 4; ++jr) {
      const int rl = wr * 64 + m * 16 + l4 * 4 + jr;
      const int pos = ti * 128 + rl;
      const int tok = list[e * NTOK + pos];
      const float pw = pairw[e * NTOK + pos];
      if (pw != 0.f) {
        #pragma unroll
        for (int n = 0; n < 4; ++n) {
          const int col = jt * 128 + wc * 64 + n * 16 + l15;
          const float v = (acc[m][n][jr] + b2[e * DDIM + col]) * pw;
          atomicAdd(&out[(size_t)tok * DDIM + col], v);
        }
      }
    }
  }
}

extern "C" void kernel_launch(void* const* d_in, const int* in_sizes, int n_in,
                              void* d_out, int out_size, void* d_ws, size_t ws_size,
                              hipStream_t stream) {
  const float* x   = (const float*)d_in[0];
  const float* gw  = (const float*)d_in[1];
  const float* gb  = (const float*)d_in[2];
  const float* f1w = (const float*)d_in[3];
  const float* f1b = (const float*)d_in[4];
  const float* f2w = (const float*)d_in[5];
  const float* f2b = (const float*)d_in[6];
  float* out = (float*)d_out;
  char* ws = (char*)d_ws;

  u16*   xb    = (u16*)(ws + WS_XB);
  u16*   w1t   = (u16*)(ws + WS_W1T);
  u16*   w2t   = (u16*)(ws + WS_W2T);
  u16*   act   = (u16*)(ws + WS_ACT);
  int*   list  = (int*)(ws + WS_LIST);
  float* pairw = (float*)(ws + WS_PAIRW);
  int*   cnt   = (int*)(ws + WS_CNT);
  float* sump  = (float*)(ws + WS_SUMP);
  int*   padc  = (int*)(ws + WS_PAD);
  int*   offs  = (int*)(ws + WS_OFF);

  (void)hipMemsetAsync(d_out, 0, (size_t)out_size * sizeof(float), stream);
  (void)hipMemsetAsync(ws + WS_CNT, 0, 64, stream);  // cnt + sump

  gate_kernel<<<NTOK / 4, 256, 0, stream>>>(x, gw, gb, xb, cnt, sump, list, pairw);
  conv_transpose<<<dim3(8192 / 64, 1024 / 64, 8), 256, 0, stream>>>(f1w, w1t, 1024, 8192);
  conv_transpose<<<dim3(1024 / 64, 4096 / 64, 8), 256, 0, stream>>>(f2w, w2t, 4096, 1024);
  route_finalize<<<1, 256, 0, stream>>>(cnt, sump, padc, offs, list, pairw, out + 8388608);
  gemm1_kernel<<<dim3(64, 64, 8), 256, 0, stream>>>(xb, w1t, f1b, list, padc, offs, act);
  gemm2_kernel<<<dim3(8, 64, 8), 256, 0, stream>>>(act, w2t, f2b, list, pairw, padc, offs, out);
}